// Round 7
// baseline (10278.464 us; speedup 1.0000x reference)
//
#include <hip/hip_runtime.h>
#include <hip/hip_bf16.h>
#include <math.h>

typedef __hip_bfloat16 bf16;
typedef __bf16 bf16x8 __attribute__((ext_vector_type(8)));
typedef __bf16 bf16x4 __attribute__((ext_vector_type(4)));
typedef float floatx4 __attribute__((ext_vector_type(4)));

#define BB 512
#define TT 80
#define DD 540
#define HH 6
#define KK 90
#define LL 6
#define HK 540      // H*K (real)
#define KKA 96      // head size padded to 96 (16B-aligned bf16x8 groups)
#define HKA 576     // H*KKA
#define NQA 1728    // 3*H*KKA  (qkv output ld, aligned head layout)
#define BT 40960    // B*T
#define TD 43200    // T*D
#define KP2 576     // GEMM K padded (9 * 64 = 18 * 32)
#define NQ2 1792    // qkv N padded to 256 (7 * 256)
#define NF 640      // ff output ld
#define NF2 768     // ff N padded to 256 (3 * 256)
#define TP 104      // attn LDS row stride (96 + 8 pad)
#define NKT2 18     // KP2 / 32

__device__ inline float toF(bf16 x) { return __bfloat162float(x); }

// ---------------- weight prep (runs every launch; graph-safe) ----------------

// QKV weights in aligned-head layout: n = sel*HKA + h*KKA + kk, zero for kk>=KK.
__global__ void prep_wqkv(const float* __restrict__ Wq,
                          const float* __restrict__ Wk,
                          const float* __restrict__ Wv,
                          bf16* __restrict__ wTt) {
    int idx = blockIdx.x * blockDim.x + threadIdx.x;
    const int total = LL * NQ2 * KP2;
    if (idx >= total) return;
    int k = idx % KP2;
    int n = (idx / KP2) % NQ2;
    int l = idx / (KP2 * NQ2);
    float v = 0.f;
    if (k < DD && n < NQA) {
        int sel = n / HKA;
        int nn = n - sel * HKA;
        int h = nn / KKA, kk = nn - h * KKA;
        if (kk < KK) {
            const float* W = (sel == 0) ? Wq : ((sel == 1) ? Wk : Wv);
            v = W[(((size_t)l * HH + h) * DD + k) * KK + kk];
        }
    }
    wTt[idx] = __float2bfloat16(v);
}

__global__ void prep_wt(const float* __restrict__ W, bf16* __restrict__ Wt) {
    int idx = blockIdx.x * blockDim.x + threadIdx.x;
    const int total = LL * NF2 * KP2;
    if (idx >= total) return;
    int k = idx % KP2;
    int n = (idx / KP2) % NF2;
    int l = idx / (KP2 * NF2);
    float v = 0.f;
    if (k < DD && n < DD)
        v = W[((size_t)l * DD + k) * DD + n];
    Wt[idx] = __float2bfloat16(v);
}

__global__ void embed_kernel(const int* __restrict__ ids,
                             const float* __restrict__ embed,
                             const float* __restrict__ pos,
                             bf16* __restrict__ xc, int rows) {
    int idx = blockIdx.x * blockDim.x + threadIdx.x;
    int total = rows * KP2;
    if (idx >= total) return;
    int d = idx % KP2;
    int bt = idx / KP2;
    float v = 0.f;
    if (d < DD) {
        int t = bt % TT;
        v = embed[(size_t)ids[bt] * DD + d] + pos[t * DD + d];
    }
    xc[idx] = __float2bfloat16(v);
}

// ---------------- 256x256 BK=32 double-buffered MFMA GEMM, 2 blocks/CU ----------------
// 512 thr = 8 waves (2M x 4N); wave owns 128x64 of C. BK=32, 18 K-tiles.
// Per buffer: 2 planes of [256 rows][32 bf16] (A, B) = 32 KiB; 2 buffers = 64 KiB
// -> 2 blocks/CU (the occupancy lever: co-resident block covers drain+barrier).
// LDS[row][c16] = global[row][c16 ^ ((row>>1)&3)] -> 0 bank conflicts (verified r3).
// Per K-tile: { stage 4 loads for tile kt+1 into other buffer (fire+forget);
//   12 ds_reads; 32 MFMA; vmcnt(0); one s_barrier }.
// Hazards: stage target's readers retired before previous trailing barrier;
// reads of tile kt gated by kt-1's vmcnt(0)+barrier.

__device__ inline void stage_tile4(const bf16* __restrict__ Ab, int lda,
                                   const bf16* __restrict__ Bb,
                                   bf16* ldsbuf, int k0, int wave, int lane) {
    const bf16* src = (wave < 4) ? Ab : Bb;          // waves 0-3: A, 4-7: B
    const int ld = (wave < 4) ? lda : KP2;
    bf16* pl = ldsbuf + (wave >> 2) * 8192;          // plane base
    const int sc = (lane & 3) ^ ((lane >> 3) & 3);   // pre-swizzled global chunk
    const int rsub = lane >> 2;                      // 0..15
#pragma unroll
    for (int jj = 0; jj < 4; ++jj) {
        int rg = (wave & 3) * 4 + jj;                // 16-row group in plane
        int row = rg * 16 + rsub;
        __builtin_amdgcn_global_load_lds(
            (const __attribute__((address_space(1))) void*)(src + (size_t)row * ld + k0 + sc * 8),
            (__attribute__((address_space(3))) void*)(pl + rg * 512 + lane * 8), 16, 0, 0);
    }
}

#define READ_A8(dst, buf)                                                       \
    _Pragma("unroll")                                                           \
    for (int i_ = 0; i_ < 8; ++i_) {                                            \
        int row_ = wr * 128 + i_ * 16 + r;                                      \
        dst[i_] = *(const bf16x8*)((buf) + row_ * 32 + ksw);                    \
    }

#define READ_B4(dst, buf)                                                       \
    _Pragma("unroll")                                                           \
    for (int j_ = 0; j_ < 4; ++j_) {                                            \
        int row_ = wc * 64 + j_ * 16 + r;                                       \
        dst[j_] = *(const bf16x8*)((buf) + 8192 + row_ * 32 + ksw);             \
    }

__global__ __launch_bounds__(512, 4) void mfma_gemm2(
    const bf16* __restrict__ A, int lda,
    const bf16* __restrict__ Bt,
    bf16* __restrict__ C, int ldc, int Nreal,
    const float* __restrict__ bias, int relu)
{
    extern __shared__ __align__(16) bf16 ldsb[];   // 2 * 16384 bf16 = 64 KiB
    const int tid = threadIdx.x;
    const int lane = tid & 63;
    const int wave = tid >> 6;
    const int wr = wave >> 2;            // 0..1  (M half)
    const int wc = wave & 3;             // 0..3  (N quarter)
    const int q = lane >> 4, r = lane & 15;

    // bijective XCD swizzle (only when grid % 8 == 0)
    int bx = blockIdx.x, by = blockIdx.y;
    {
        int nwg = gridDim.x * gridDim.y;
        if ((nwg & 7) == 0) {
            int orig = by * gridDim.x + bx;
            int per = nwg >> 3;
            int swz = (orig & 7) * per + (orig >> 3);
            bx = swz % gridDim.x;
            by = swz / gridDim.x;
        }
    }
    const int row0 = by * 256;
    const int col0 = bx * 256;

    floatx4 acc[8][4];
#pragma unroll
    for (int i = 0; i < 8; ++i)
#pragma unroll
        for (int j = 0; j < 4; ++j) acc[i][j] = (floatx4){0.f, 0.f, 0.f, 0.f};

    const bf16* Ab = A + (size_t)row0 * lda;
    const bf16* Bb = Bt + (size_t)col0 * KP2;

    const int ksw = (q ^ ((r >> 1) & 3)) * 8;    // read-side chunk swizzle

    // prologue: stage tile 0 into buf0, drain, publish
    stage_tile4(Ab, lda, Bb, ldsb, 0, wave, lane);
    asm volatile("s_waitcnt vmcnt(0)" ::: "memory");
    __builtin_amdgcn_sched_barrier(0);
    __builtin_amdgcn_s_barrier();
    __builtin_amdgcn_sched_barrier(0);

    for (int kt = 0; kt < NKT2; ++kt) {
        bf16* buf  = ldsb + (kt & 1) * 16384;        // tile kt (landed)
        bf16* sbuf = ldsb + ((kt + 1) & 1) * 16384;  // stage target

        // fire-and-forget: stage tile kt+1 (hidden under this tile's compute)
        if (kt + 1 < NKT2)
            stage_tile4(Ab, lda, Bb, sbuf, (kt + 1) * 32, wave, lane);

        bf16x8 a0[8], b0[4];
        READ_A8(a0, buf);
        READ_B4(b0, buf);

        __builtin_amdgcn_s_setprio(1);
#pragma unroll
        for (int i = 0; i < 8; ++i)
#pragma unroll
            for (int j = 0; j < 4; ++j)
                acc[i][j] = __builtin_amdgcn_mfma_f32_16x16x32_bf16(
                    a0[i], b0[j], acc[i][j], 0, 0, 0);
        __builtin_amdgcn_s_setprio(0);

        asm volatile("s_waitcnt vmcnt(0)" ::: "memory");
        __builtin_amdgcn_sched_barrier(0);
        __builtin_amdgcn_s_barrier();
        __builtin_amdgcn_sched_barrier(0);
    }

    // epilogue: row = row0 + wr*128 + mi*16 + q*4 + reg, col = col0 + wc*64 + ni*16 + r
#pragma unroll
    for (int mi = 0; mi < 8; ++mi) {
        int m0 = row0 + wr * 128 + mi * 16 + q * 4;
#pragma unroll
        for (int ni = 0; ni < 4; ++ni) {
            int n = col0 + wc * 64 + ni * 16 + r;
            if (n < ldc) {
                bool valid = (n < Nreal);
                float bv = (valid && bias) ? bias[n] : 0.f;
#pragma unroll
                for (int reg = 0; reg < 4; ++reg) {
                    float v = acc[mi][ni][reg] + bv;
                    if (relu) v = fmaxf(v, 0.f);
                    if (!valid) v = 0.f;
                    C[(size_t)(m0 + reg) * ldc + n] = __float2bfloat16(v);
                }
            }
        }
    }
}

// ---------------- MFMA attention (aligned-head qkv layout, vectorized staging) ----------------
__global__ __launch_bounds__(320) void attn_mfma(const bf16* __restrict__ qkv,
                                                 bf16* __restrict__ obuf) {
    extern __shared__ bf16 lds[];
    bf16* Qs = lds;                    // 80*TP
    bf16* Ks = lds + 80 * TP;          // 80*TP (becomes P)
    bf16* Vt = lds + 160 * TP;         // 96*TP
    __bf16* Vtb = (__bf16*)Vt;
    const int b = blockIdx.x / HH, h = blockIdx.x % HH;
    const int tid = threadIdx.x;
    const int lane = tid & 63;
    const int w = tid >> 6;            // wave 0..4
    const int q = lane >> 4, r = lane & 15;
    const bf16* base = qkv + (size_t)b * TT * NQA + h * KKA;

    // stage Q, K (pad cols [90,96) are zero in qkv by construction); V transposed
    for (int i = tid; i < TT * 12; i += 320) {
        int t = i / 12, kg = i % 12;
        const bf16* qr2 = base + (size_t)t * NQA + kg * 8;
        bf16x8 qv = *(const bf16x8*)qr2;
        bf16x8 kv2 = *(const bf16x8*)(qr2 + HKA);
        bf16x8 vv = *(const bf16x8*)(qr2 + 2 * HKA);
        *(bf16x8*)(Qs + t * TP + kg * 8) = qv;
        *(bf16x8*)(Ks + t * TP + kg * 8) = kv2;
#pragma unroll
        for (int j = 0; j < 8; ++j)
            Vtb[(kg * 8 + j) * TP + t] = vv[j];
    }
    // zero Vt s-pad [80,96) so PV pad terms are exactly 0
    for (int i = tid; i < 96 * 2; i += 320) {
        int kv = i >> 1, sg = i & 1;
        *(bf16x8*)(Vt + kv * TP + 80 + sg * 8) = (bf16x8)(__bf16)0.0f;
    }
    __syncthreads();

    // S-GEMM: wave w -> columns s in [16w, 16w+16)
    floatx4 acc[5];
#pragma unroll
    for (int i = 0; i < 5; ++i) acc[i] = (floatx4){0.f, 0.f, 0.f, 0.f};
    bf16x8 bf[3];
#pragma unroll
    for (int ks = 0; ks < 3; ++ks)
        bf[ks] = *(const bf16x8*)(Ks + (16 * w + r) * TP + ks * 32 + q * 8);
#pragma unroll
    for (int ti = 0; ti < 5; ++ti) {
#pragma unroll
        for (int ks = 0; ks < 3; ++ks) {
            bf16x8 af = *(const bf16x8*)(Qs + (16 * ti + r) * TP + ks * 32 + q * 8);
            acc[ti] = __builtin_amdgcn_mfma_f32_16x16x32_bf16(af, bf[ks], acc[ti], 0, 0, 0);
        }
    }

    const float scale = 0.105409255338946f;  // 90^-0.5
    float m = -1e30f;
#pragma unroll
    for (int ti = 0; ti < 5; ++ti)
#pragma unroll
        for (int reg = 0; reg < 4; ++reg) {
            acc[ti][reg] *= scale;
            m = fmaxf(m, acc[ti][reg]);
        }
    m = fmaxf(m, __shfl_xor(m, 16));
    m = fmaxf(m, __shfl_xor(m, 32));
    float sum = 0.f;
    float e[5][4];
#pragma unroll
    for (int ti = 0; ti < 5; ++ti)
#pragma unroll
        for (int reg = 0; reg < 4; ++reg) {
            e[ti][reg] = __expf(acc[ti][reg] - m);
            sum += e[ti][reg];
        }
    sum += __shfl_xor(sum, 16);
    sum += __shfl_xor(sum, 32);
    float inv = 1.f / sum;

    __syncthreads();   // all Ks reads done before P overwrites it

    bf16* P = Ks;
#pragma unroll
    for (int ti = 0; ti < 5; ++ti)
#pragma unroll
        for (int reg = 0; reg < 4; ++reg)
            P[(16 * ti + q * 4 + reg) * TP + 16 * w + r] =
                __float2bfloat16(e[ti][reg] * inv);
    for (int i = tid; i < TT * 2; i += 320) {
        int t2 = i >> 1, sg = i & 1;
        *(bf16x8*)(P + t2 * TP + 80 + sg * 8) = (bf16x8)(__bf16)0.0f;
    }
    __syncthreads();

    bf16x8 af2[3];
#pragma unroll
    for (int ks = 0; ks < 3; ++ks)
        af2[ks] = *(const bf16x8*)(P + (16 * w + r) * TP + ks * 32 + q * 8);
    bf16* ob = obuf + ((size_t)b * TT) * NF + h * KK;
#pragma unroll
    for (int nt = 0; nt < 6; ++nt) {
        floatx4 o = (floatx4){0.f, 0.f, 0.f, 0.f};
#pragma unroll
        for (int ks = 0; ks < 3; ++ks) {
            bf16x8 bv = *(const bf16x8*)(Vt + (16 * nt + r) * TP + ks * 32 + q * 8);
            o = __builtin_amdgcn_mfma_f32_16x16x32_bf16(af2[ks], bv, o, 0, 0, 0);
        }
        int kv = 16 * nt + r;
        if (kv < KK) {
#pragma unroll
            for (int reg = 0; reg < 4; ++reg) {
                int t2 = 16 * w + q * 4 + reg;
                ob[(size_t)t2 * NF + kv] = __float2bfloat16(o[reg]);
            }
        }
    }
}

// ---------------- x = LN(delta + x) * g + b  — one wave per row, vectorized ----------------
__global__ __launch_bounds__(256) void add_ln_kernel(const bf16* __restrict__ delta,
                                                     bf16* __restrict__ x,
                                                     const float* __restrict__ g,
                                                     const float* __restrict__ bta,
                                                     int nrows) {
    const int w = threadIdx.x >> 6;
    const int lane = threadIdx.x & 63;
    const int row = blockIdx.x * 4 + w;
    if (row >= nrows) return;
    const bf16* dr = delta + (size_t)row * NF;
    bf16* xr = x + (size_t)row * KP2;

    float v[3][4];
    float s1 = 0.f, s2 = 0.f;
#pragma unroll
    for (int s = 0; s < 3; ++s) {
        int c = s * 256 + lane * 4;
        if (c < DD) {
            bf16x4 dv = *(const bf16x4*)(dr + c);
            bf16x4 xv = *(const bf16x4*)(xr + c);
#pragma unroll
            for (int j = 0; j < 4; ++j) {
                float t = (float)dv[j] + (float)xv[j];
                v[s][j] = t;
                s1 += t; s2 += t * t;
            }
        } else {
#pragma unroll
            for (int j = 0; j < 4; ++j) v[s][j] = 0.f;
        }
    }
#pragma unroll
    for (int o = 32; o > 0; o >>= 1) {
        s1 += __shfl_xor(s1, o, 64);
        s2 += __shfl_xor(s2, o, 64);
    }
    const float mean = s1 * (1.f / DD);
    const float var = s2 * (1.f / DD) - mean * mean;
    const float rstd = rsqrtf(var + 1e-5f);
#pragma unroll
    for (int s = 0; s < 3; ++s) {
        int c = s * 256 + lane * 4;
        if (c < DD) {
            float4 gv = *(const float4*)(g + c);
            float4 bv = *(const float4*)(bta + c);
            bf16x4 ov;
            ov[0] = (__bf16)((v[s][0] - mean) * rstd * gv.x + bv.x);
            ov[1] = (__bf16)((v[s][1] - mean) * rstd * gv.y + bv.y);
            ov[2] = (__bf16)((v[s][2] - mean) * rstd * gv.z + bv.z);
            ov[3] = (__bf16)((v[s][3] - mean) * rstd * gv.w + bv.w);
            *(bf16x4*)(xr + c) = ov;
        }
    }
}

__global__ __launch_bounds__(256) void final_kernel(const bf16* __restrict__ xc,
                                                    const float* __restrict__ Wc,
                                                    const float* __restrict__ bc,
                                                    float* __restrict__ out) {
    int b = blockIdx.x;
    int tid = threadIdx.x;
    const bf16* xb = xc + (size_t)b * TT * KP2;
    float s = 0.f;
    for (int i = tid; i < TD; i += 256) {
        int t = i / DD, d = i - t * DD;
        s += toF(xb[(size_t)t * KP2 + d]) * Wc[i];
    }
    for (int o = 32; o > 0; o >>= 1) s += __shfl_down(s, o, 64);
    __shared__ float red[4];
    int lane = tid & 63, w = tid >> 6;
    if (lane == 0) red[w] = s;
    __syncthreads();
    if (tid == 0) out[b] = red[0] + red[1] + red[2] + red[3] + bc[0];
}

extern "C" void kernel_launch(void* const* d_in, const int* in_sizes, int n_in,
                              void* d_out, int out_size, void* d_ws, size_t ws_size,
                              hipStream_t stream) {
    const int* ids    = (const int*)d_in[0];
    const float* embed = (const float*)d_in[1];
    const float* pos  = (const float*)d_in[2];
    const float* Wq   = (const float*)d_in[3];
    const float* Wk   = (const float*)d_in[4];
    const float* Wv   = (const float*)d_in[5];
    const float* W1   = (const float*)d_in[6];
    const float* b1   = (const float*)d_in[7];
    const float* W2   = (const float*)d_in[8];
    const float* b2   = (const float*)d_in[9];
    const float* ln1g = (const float*)d_in[10];
    const float* ln1b = (const float*)d_in[11];
    const float* ln2g = (const float*)d_in[12];
    const float* ln2b = (const float*)d_in[13];
    const float* Wc   = (const float*)d_in[14];
    const float* bc   = (const float*)d_in[15];
    float* out = (float*)d_out;

    const size_t wqkvB = (size_t)LL * NQ2 * KP2 * 2;
    const size_t wffB  = (size_t)LL * NF2 * KP2 * 2;
    const size_t fixed = wqkvB + 2 * wffB;
    const size_t perB  = (size_t)TT * 2 * (KP2 + NQA + NF);

    int bch = BB;
    while (bch > 16 && fixed + (size_t)bch * perB > ws_size) bch >>= 1;
    int nch = BB / bch;
    int rows = bch * TT;           // multiple of 256 for bch >= 16

    char* p = (char*)d_ws;
    bf16* wTt = (bf16*)p;  p += wqkvB;
    bf16* W1t = (bf16*)p;  p += wffB;
    bf16* W2t = (bf16*)p;  p += wffB;
    bf16* xc  = (bf16*)p;  p += (size_t)rows * KP2 * 2;
    bf16* scr = (bf16*)p;  p += (size_t)rows * NQA * 2;
    bf16* dch = (bf16*)p;

    prep_wqkv<<<(LL * NQ2 * KP2 + 255) / 256, 256, 0, stream>>>(Wq, Wk, Wv, wTt);
    prep_wt<<<(LL * NF2 * KP2 + 255) / 256, 256, 0, stream>>>(W1, W1t);
    prep_wt<<<(LL * NF2 * KP2 + 255) / 256, 256, 0, stream>>>(W2, W2t);

    dim3 gq(NQ2 / 256, rows / 256);
    dim3 gf(NF2 / 256, rows / 256);
    const size_t gemm_lds = 2 * 16384 * sizeof(bf16);      // 64 KiB -> 2 blocks/CU
    const size_t attn_lds = (size_t)(160 + 96) * TP * 2;   // 53,248 B
    const int lnGrid = (rows + 3) / 4;

    for (int c = 0; c < nch; ++c) {
        embed_kernel<<<(rows * KP2 + 255) / 256, 256, 0, stream>>>(
            ids + (size_t)c * rows, embed, pos, xc, rows);
        for (int l = 0; l < LL; ++l) {
            mfma_gemm2<<<gq, 512, gemm_lds, stream>>>(
                xc, KP2, wTt + (size_t)l * NQ2 * KP2, scr, NQA, NQA,
                (const float*)nullptr, 0);
            attn_mfma<<<bch * HH, 320, attn_lds, stream>>>(scr, dch);
            add_ln_kernel<<<lnGrid, 256, 0, stream>>>(dch, xc, ln1g + l * DD, ln1b + l * DD, rows);
            mfma_gemm2<<<gf, 512, gemm_lds, stream>>>(
                xc, KP2, W1t + (size_t)l * NF2 * KP2, scr, NF, HK,
                b1 + (size_t)l * HK, 1);
            mfma_gemm2<<<gf, 512, gemm_lds, stream>>>(
                scr, NF, W2t + (size_t)l * NF2 * KP2, dch, NF, DD,
                b2 + (size_t)l * DD, 0);
            add_ln_kernel<<<lnGrid, 256, 0, stream>>>(dch, xc, ln2g + l * DD, ln2b + l * DD, rows);
        }
        final_kernel<<<bch, 256, 0, stream>>>(xc, Wc, bc, out + (size_t)c * bch);
    }
}

// Round 8
// 2127.665 us; speedup vs baseline: 4.8309x; 4.8309x over previous
//
#include <hip/hip_runtime.h>
#include <hip/hip_bf16.h>
#include <math.h>

typedef __hip_bfloat16 bf16;
typedef __bf16 bf16x8 __attribute__((ext_vector_type(8)));
typedef __bf16 bf16x4 __attribute__((ext_vector_type(4)));
typedef float floatx4 __attribute__((ext_vector_type(4)));

#define BB 512
#define TT 80
#define DD 540
#define HH 6
#define KK 90
#define LL 6
#define HK 540      // H*K (real)
#define KKA 96      // head size padded to 96 (16B-aligned bf16x8 groups)
#define HKA 576     // H*KKA
#define NQA 1728    // 3*H*KKA  (qkv output ld, aligned head layout)
#define BT 40960    // B*T
#define TD 43200    // T*D
#define KP2 576     // GEMM K padded (18 * 32)
#define NQ2 1792    // qkv N padded to 256 (7 * 256)
#define NF 640      // ff output ld
#define NF2 768     // ff N padded to 256 (3 * 256)
#define TP 104      // attn LDS row stride (96 + 8 pad)
#define NKT2 18     // KP2 / 32
#define BUFSZ 12288 // per-buffer bf16: A 128*32 + B 256*32

__device__ inline float toF(bf16 x) { return __bfloat162float(x); }

// ---------------- weight prep (runs every launch; graph-safe) ----------------

// QKV weights in aligned-head layout: n = sel*HKA + h*KKA + kk, zero for kk>=KK.
__global__ void prep_wqkv(const float* __restrict__ Wq,
                          const float* __restrict__ Wk,
                          const float* __restrict__ Wv,
                          bf16* __restrict__ wTt) {
    int idx = blockIdx.x * blockDim.x + threadIdx.x;
    const int total = LL * NQ2 * KP2;
    if (idx >= total) return;
    int k = idx % KP2;
    int n = (idx / KP2) % NQ2;
    int l = idx / (KP2 * NQ2);
    float v = 0.f;
    if (k < DD && n < NQA) {
        int sel = n / HKA;
        int nn = n - sel * HKA;
        int h = nn / KKA, kk = nn - h * KKA;
        if (kk < KK) {
            const float* W = (sel == 0) ? Wq : ((sel == 1) ? Wk : Wv);
            v = W[(((size_t)l * HH + h) * DD + k) * KK + kk];
        }
    }
    wTt[idx] = __float2bfloat16(v);
}

__global__ void prep_wt(const float* __restrict__ W, bf16* __restrict__ Wt) {
    int idx = blockIdx.x * blockDim.x + threadIdx.x;
    const int total = LL * NF2 * KP2;
    if (idx >= total) return;
    int k = idx % KP2;
    int n = (idx / KP2) % NF2;
    int l = idx / (KP2 * NF2);
    float v = 0.f;
    if (k < DD && n < DD)
        v = W[((size_t)l * DD + k) * DD + n];
    Wt[idx] = __float2bfloat16(v);
}

__global__ void embed_kernel(const int* __restrict__ ids,
                             const float* __restrict__ embed,
                             const float* __restrict__ pos,
                             bf16* __restrict__ xc, int rows) {
    int idx = blockIdx.x * blockDim.x + threadIdx.x;
    int total = rows * KP2;
    if (idx >= total) return;
    int d = idx % KP2;
    int bt = idx / KP2;
    float v = 0.f;
    if (d < DD) {
        int t = bt % TT;
        v = embed[(size_t)ids[bt] * DD + d] + pos[t * DD + d];
    }
    xc[idx] = __float2bfloat16(v);
}

// ---------------- 128x256 BK=32 double-buffered MFMA GEMM, 2 blocks/CU ----------------
// 512 thr = 8 waves (2M x 4N); wave owns 64x64 of C -> acc[4][4] = 64 VGPR
// (fits the 128-VGPR cap of launch_bounds(512,4) WITHOUT spilling; round-7's
// 128x64/wave could not). Per buffer: A[128][32] + B[256][32] planes = 24 KiB;
// dbuf 48 KiB -> 2 blocks/CU (VGPR-bound). Co-resident block hides each
// block's per-tile vmcnt+barrier drain (m114 overlap).
// LDS[row][c16] = global[row][c16 ^ ((row>>1)&3)] -> 0 bank conflicts (verified r3).
// Per K-tile: { 3 stage loads for tile kt+1 (other buffer, fire+forget);
//   8 ds_reads; 16 MFMA; vmcnt(0); one s_barrier }.

__device__ inline void stage3(const bf16* __restrict__ Ab, int lda,
                              const bf16* __restrict__ Bb,
                              bf16* ldsbuf, int k0, int tid) {
    // 1536 16B-chunk slots: [0,512) = A rows 0..127 x 4 chunks,
    // [512,1536) = B rows 0..255 x 4 chunks. Wave's 64 slots contiguous,
    // single plane -> dest = wave-uniform base + lane*16.
#pragma unroll
    for (int i = 0; i < 3; ++i) {
        int s = tid + i * 512;
        int isB = (s >= 512) ? 1 : 0;            // wave-uniform
        int s2 = s - isB * 512;
        int row = s2 >> 2, c = s2 & 3;
        int cs = c ^ ((row >> 1) & 3);           // pre-swizzled global chunk
        const bf16* src = isB ? (Bb + (size_t)row * KP2 + k0 + cs * 8)
                              : (Ab + (size_t)row * lda + k0 + cs * 8);
        bf16* dst = ldsbuf + isB * 4096 + s2 * 8;
        __builtin_amdgcn_global_load_lds(
            (const __attribute__((address_space(1))) void*)src,
            (__attribute__((address_space(3))) void*)dst, 16, 0, 0);
    }
}

__global__ __launch_bounds__(512, 4) void mfma_gemm2(
    const bf16* __restrict__ A, int lda,
    const bf16* __restrict__ Bt,
    bf16* __restrict__ C, int ldc, int Nreal,
    const float* __restrict__ bias, int relu)
{
    extern __shared__ __align__(16) bf16 ldsb[];   // 2 * 12288 bf16 = 48 KiB
    const int tid = threadIdx.x;
    const int lane = tid & 63;
    const int wave = tid >> 6;
    const int wr = wave >> 2;            // 0..1  (M half, 64 rows)
    const int wc = wave & 3;             // 0..3  (N quarter, 64 cols)
    const int q = lane >> 4, r = lane & 15;

    // bijective XCD swizzle (only when grid % 8 == 0)
    int bx = blockIdx.x, by = blockIdx.y;
    {
        int nwg = gridDim.x * gridDim.y;
        if ((nwg & 7) == 0) {
            int orig = by * gridDim.x + bx;
            int per = nwg >> 3;
            int swz = (orig & 7) * per + (orig >> 3);
            bx = swz % gridDim.x;
            by = swz / gridDim.x;
        }
    }
    const int row0 = by * 128;
    const int col0 = bx * 256;

    floatx4 acc[4][4];
#pragma unroll
    for (int i = 0; i < 4; ++i)
#pragma unroll
        for (int j = 0; j < 4; ++j) acc[i][j] = (floatx4){0.f, 0.f, 0.f, 0.f};

    const bf16* Ab = A + (size_t)row0 * lda;
    const bf16* Bb = Bt + (size_t)col0 * KP2;

    const int ksw = (q ^ ((r >> 1) & 3)) * 8;    // read-side chunk swizzle

    // prologue: stage tile 0 into buf0, drain, publish
    stage3(Ab, lda, Bb, ldsb, 0, tid);
    asm volatile("s_waitcnt vmcnt(0)" ::: "memory");
    __builtin_amdgcn_sched_barrier(0);
    __builtin_amdgcn_s_barrier();
    __builtin_amdgcn_sched_barrier(0);

    for (int kt = 0; kt < NKT2; ++kt) {
        bf16* buf  = ldsb + (kt & 1) * BUFSZ;        // tile kt (landed)
        bf16* sbuf = ldsb + ((kt + 1) & 1) * BUFSZ;  // stage target

        // fire-and-forget: stage tile kt+1 (hidden under this tile's compute)
        if (kt + 1 < NKT2)
            stage3(Ab, lda, Bb, sbuf, (kt + 1) * 32, tid);

        bf16x8 a0[4], b0[4];
#pragma unroll
        for (int i = 0; i < 4; ++i) {
            int row_ = wr * 64 + i * 16 + r;
            a0[i] = *(const bf16x8*)(buf + row_ * 32 + ksw);
        }
#pragma unroll
        for (int j = 0; j < 4; ++j) {
            int row_ = wc * 64 + j * 16 + r;
            b0[j] = *(const bf16x8*)(buf + 4096 + row_ * 32 + ksw);
        }

        __builtin_amdgcn_s_setprio(1);
#pragma unroll
        for (int i = 0; i < 4; ++i)
#pragma unroll
            for (int j = 0; j < 4; ++j)
                acc[i][j] = __builtin_amdgcn_mfma_f32_16x16x32_bf16(
                    a0[i], b0[j], acc[i][j], 0, 0, 0);
        __builtin_amdgcn_s_setprio(0);

        asm volatile("s_waitcnt vmcnt(0)" ::: "memory");
        __builtin_amdgcn_sched_barrier(0);
        __builtin_amdgcn_s_barrier();
        __builtin_amdgcn_sched_barrier(0);
    }

    // epilogue: row = row0 + wr*64 + i*16 + q*4 + reg, col = col0 + wc*64 + j*16 + r
#pragma unroll
    for (int mi = 0; mi < 4; ++mi) {
        int m0 = row0 + wr * 64 + mi * 16 + q * 4;
#pragma unroll
        for (int ni = 0; ni < 4; ++ni) {
            int n = col0 + wc * 64 + ni * 16 + r;
            if (n < ldc) {
                bool valid = (n < Nreal);
                float bv = (valid && bias) ? bias[n] : 0.f;
#pragma unroll
                for (int reg = 0; reg < 4; ++reg) {
                    float v = acc[mi][ni][reg] + bv;
                    if (relu) v = fmaxf(v, 0.f);
                    if (!valid) v = 0.f;
                    C[(size_t)(m0 + reg) * ldc + n] = __float2bfloat16(v);
                }
            }
        }
    }
}

// ---------------- MFMA attention (aligned-head qkv layout, vectorized staging) ----------------
__global__ __launch_bounds__(320) void attn_mfma(const bf16* __restrict__ qkv,
                                                 bf16* __restrict__ obuf) {
    extern __shared__ bf16 lds[];
    bf16* Qs = lds;                    // 80*TP
    bf16* Ks = lds + 80 * TP;          // 80*TP (becomes P)
    bf16* Vt = lds + 160 * TP;         // 96*TP
    __bf16* Vtb = (__bf16*)Vt;
    const int b = blockIdx.x / HH, h = blockIdx.x % HH;
    const int tid = threadIdx.x;
    const int lane = tid & 63;
    const int w = tid >> 6;            // wave 0..4
    const int q = lane >> 4, r = lane & 15;
    const bf16* base = qkv + (size_t)b * TT * NQA + h * KKA;

    // stage Q, K (pad cols [90,96) are zero in qkv by construction); V transposed
    for (int i = tid; i < TT * 12; i += 320) {
        int t = i / 12, kg = i % 12;
        const bf16* qr2 = base + (size_t)t * NQA + kg * 8;
        bf16x8 qv = *(const bf16x8*)qr2;
        bf16x8 kv2 = *(const bf16x8*)(qr2 + HKA);
        bf16x8 vv = *(const bf16x8*)(qr2 + 2 * HKA);
        *(bf16x8*)(Qs + t * TP + kg * 8) = qv;
        *(bf16x8*)(Ks + t * TP + kg * 8) = kv2;
#pragma unroll
        for (int j = 0; j < 8; ++j)
            Vtb[(kg * 8 + j) * TP + t] = vv[j];
    }
    // zero Vt s-pad [80,96) so PV pad terms are exactly 0
    for (int i = tid; i < 96 * 2; i += 320) {
        int kv = i >> 1, sg = i & 1;
        *(bf16x8*)(Vt + kv * TP + 80 + sg * 8) = (bf16x8)(__bf16)0.0f;
    }
    __syncthreads();

    // S-GEMM: wave w -> columns s in [16w, 16w+16)
    floatx4 acc[5];
#pragma unroll
    for (int i = 0; i < 5; ++i) acc[i] = (floatx4){0.f, 0.f, 0.f, 0.f};
    bf16x8 bf[3];
#pragma unroll
    for (int ks = 0; ks < 3; ++ks)
        bf[ks] = *(const bf16x8*)(Ks + (16 * w + r) * TP + ks * 32 + q * 8);
#pragma unroll
    for (int ti = 0; ti < 5; ++ti) {
#pragma unroll
        for (int ks = 0; ks < 3; ++ks) {
            bf16x8 af = *(const bf16x8*)(Qs + (16 * ti + r) * TP + ks * 32 + q * 8);
            acc[ti] = __builtin_amdgcn_mfma_f32_16x16x32_bf16(af, bf[ks], acc[ti], 0, 0, 0);
        }
    }

    const float scale = 0.105409255338946f;  // 90^-0.5
    float m = -1e30f;
#pragma unroll
    for (int ti = 0; ti < 5; ++ti)
#pragma unroll
        for (int reg = 0; reg < 4; ++reg) {
            acc[ti][reg] *= scale;
            m = fmaxf(m, acc[ti][reg]);
        }
    m = fmaxf(m, __shfl_xor(m, 16));
    m = fmaxf(m, __shfl_xor(m, 32));
    float sum = 0.f;
    float e[5][4];
#pragma unroll
    for (int ti = 0; ti < 5; ++ti)
#pragma unroll
        for (int reg = 0; reg < 4; ++reg) {
            e[ti][reg] = __expf(acc[ti][reg] - m);
            sum += e[ti][reg];
        }
    sum += __shfl_xor(sum, 16);
    sum += __shfl_xor(sum, 32);
    float inv = 1.f / sum;

    __syncthreads();   // all Ks reads done before P overwrites it

    bf16* P = Ks;
#pragma unroll
    for (int ti = 0; ti < 5; ++ti)
#pragma unroll
        for (int reg = 0; reg < 4; ++reg)
            P[(16 * ti + q * 4 + reg) * TP + 16 * w + r] =
                __float2bfloat16(e[ti][reg] * inv);
    for (int i = tid; i < TT * 2; i += 320) {
        int t2 = i >> 1, sg = i & 1;
        *(bf16x8*)(P + t2 * TP + 80 + sg * 8) = (bf16x8)(__bf16)0.0f;
    }
    __syncthreads();

    bf16x8 af2[3];
#pragma unroll
    for (int ks = 0; ks < 3; ++ks)
        af2[ks] = *(const bf16x8*)(P + (16 * w + r) * TP + ks * 32 + q * 8);
    bf16* ob = obuf + ((size_t)b * TT) * NF + h * KK;
#pragma unroll
    for (int nt = 0; nt < 6; ++nt) {
        floatx4 o = (floatx4){0.f, 0.f, 0.f, 0.f};
#pragma unroll
        for (int ks = 0; ks < 3; ++ks) {
            bf16x8 bv = *(const bf16x8*)(Vt + (16 * nt + r) * TP + ks * 32 + q * 8);
            o = __builtin_amdgcn_mfma_f32_16x16x32_bf16(af2[ks], bv, o, 0, 0, 0);
        }
        int kv = 16 * nt + r;
        if (kv < KK) {
#pragma unroll
            for (int reg = 0; reg < 4; ++reg) {
                int t2 = 16 * w + q * 4 + reg;
                ob[(size_t)t2 * NF + kv] = __float2bfloat16(o[reg]);
            }
        }
    }
}

// ---------------- x = LN(delta + x) * g + b  — one wave per row, vectorized ----------------
__global__ __launch_bounds__(256) void add_ln_kernel(const bf16* __restrict__ delta,
                                                     bf16* __restrict__ x,
                                                     const float* __restrict__ g,
                                                     const float* __restrict__ bta,
                                                     int nrows) {
    const int w = threadIdx.x >> 6;
    const int lane = threadIdx.x & 63;
    const int row = blockIdx.x * 4 + w;
    if (row >= nrows) return;
    const bf16* dr = delta + (size_t)row * NF;
    bf16* xr = x + (size_t)row * KP2;

    float v[3][4];
    float s1 = 0.f, s2 = 0.f;
#pragma unroll
    for (int s = 0; s < 3; ++s) {
        int c = s * 256 + lane * 4;
        if (c < DD) {
            bf16x4 dv = *(const bf16x4*)(dr + c);
            bf16x4 xv = *(const bf16x4*)(xr + c);
#pragma unroll
            for (int j = 0; j < 4; ++j) {
                float t = (float)dv[j] + (float)xv[j];
                v[s][j] = t;
                s1 += t; s2 += t * t;
            }
        } else {
#pragma unroll
            for (int j = 0; j < 4; ++j) v[s][j] = 0.f;
        }
    }
#pragma unroll
    for (int o = 32; o > 0; o >>= 1) {
        s1 += __shfl_xor(s1, o, 64);
        s2 += __shfl_xor(s2, o, 64);
    }
    const float mean = s1 * (1.f / DD);
    const float var = s2 * (1.f / DD) - mean * mean;
    const float rstd = rsqrtf(var + 1e-5f);
#pragma unroll
    for (int s = 0; s < 3; ++s) {
        int c = s * 256 + lane * 4;
        if (c < DD) {
            float4 gv = *(const float4*)(g + c);
            float4 bv = *(const float4*)(bta + c);
            bf16x4 ov;
            ov[0] = (__bf16)((v[s][0] - mean) * rstd * gv.x + bv.x);
            ov[1] = (__bf16)((v[s][1] - mean) * rstd * gv.y + bv.y);
            ov[2] = (__bf16)((v[s][2] - mean) * rstd * gv.z + bv.z);
            ov[3] = (__bf16)((v[s][3] - mean) * rstd * gv.w + bv.w);
            *(bf16x4*)(xr + c) = ov;
        }
    }
}

__global__ __launch_bounds__(256) void final_kernel(const bf16* __restrict__ xc,
                                                    const float* __restrict__ Wc,
                                                    const float* __restrict__ bc,
                                                    float* __restrict__ out) {
    int b = blockIdx.x;
    int tid = threadIdx.x;
    const bf16* xb = xc + (size_t)b * TT * KP2;
    float s = 0.f;
    for (int i = tid; i < TD; i += 256) {
        int t = i / DD, d = i - t * DD;
        s += toF(xb[(size_t)t * KP2 + d]) * Wc[i];
    }
    for (int o = 32; o > 0; o >>= 1) s += __shfl_down(s, o, 64);
    __shared__ float red[4];
    int lane = tid & 63, w = tid >> 6;
    if (lane == 0) red[w] = s;
    __syncthreads();
    if (tid == 0) out[b] = red[0] + red[1] + red[2] + red[3] + bc[0];
}

extern "C" void kernel_launch(void* const* d_in, const int* in_sizes, int n_in,
                              void* d_out, int out_size, void* d_ws, size_t ws_size,
                              hipStream_t stream) {
    const int* ids    = (const int*)d_in[0];
    const float* embed = (const float*)d_in[1];
    const float* pos  = (const float*)d_in[2];
    const float* Wq   = (const float*)d_in[3];
    const float* Wk   = (const float*)d_in[4];
    const float* Wv   = (const float*)d_in[5];
    const float* W1   = (const float*)d_in[6];
    const float* b1   = (const float*)d_in[7];
    const float* W2   = (const float*)d_in[8];
    const float* b2   = (const float*)d_in[9];
    const float* ln1g = (const float*)d_in[10];
    const float* ln1b = (const float*)d_in[11];
    const float* ln2g = (const float*)d_in[12];
    const float* ln2b = (const float*)d_in[13];
    const float* Wc   = (const float*)d_in[14];
    const float* bc   = (const float*)d_in[15];
    float* out = (float*)d_out;

    const size_t wqkvB = (size_t)LL * NQ2 * KP2 * 2;
    const size_t wffB  = (size_t)LL * NF2 * KP2 * 2;
    const size_t fixed = wqkvB + 2 * wffB;
    const size_t perB  = (size_t)TT * 2 * (KP2 + NQA + NF);

    int bch = BB;
    while (bch > 16 && fixed + (size_t)bch * perB > ws_size) bch >>= 1;
    int nch = BB / bch;
    int rows = bch * TT;           // multiple of 256 for bch >= 16

    char* p = (char*)d_ws;
    bf16* wTt = (bf16*)p;  p += wqkvB;
    bf16* W1t = (bf16*)p;  p += wffB;
    bf16* W2t = (bf16*)p;  p += wffB;
    bf16* xc  = (bf16*)p;  p += (size_t)rows * KP2 * 2;
    bf16* scr = (bf16*)p;  p += (size_t)rows * NQA * 2;
    bf16* dch = (bf16*)p;

    prep_wqkv<<<(LL * NQ2 * KP2 + 255) / 256, 256, 0, stream>>>(Wq, Wk, Wv, wTt);
    prep_wt<<<(LL * NF2 * KP2 + 255) / 256, 256, 0, stream>>>(W1, W1t);
    prep_wt<<<(LL * NF2 * KP2 + 255) / 256, 256, 0, stream>>>(W2, W2t);

    dim3 gq(NQ2 / 256, rows / 128);
    dim3 gf(NF2 / 256, rows / 128);
    const size_t gemm_lds = 2 * BUFSZ * sizeof(bf16);      // 48 KiB -> 2 blocks/CU
    const size_t attn_lds = (size_t)(160 + 96) * TP * 2;   // 53,248 B
    const int lnGrid = (rows + 3) / 4;

    for (int c = 0; c < nch; ++c) {
        embed_kernel<<<(rows * KP2 + 255) / 256, 256, 0, stream>>>(
            ids + (size_t)c * rows, embed, pos, xc, rows);
        for (int l = 0; l < LL; ++l) {
            mfma_gemm2<<<gq, 512, gemm_lds, stream>>>(
                xc, KP2, wTt + (size_t)l * NQ2 * KP2, scr, NQA, NQA,
                (const float*)nullptr, 0);
            attn_mfma<<<bch * HH, 320, attn_lds, stream>>>(scr, dch);
            add_ln_kernel<<<lnGrid, 256, 0, stream>>>(dch, xc, ln1g + l * DD, ln1b + l * DD, rows);
            mfma_gemm2<<<gf, 512, gemm_lds, stream>>>(
                xc, KP2, W1t + (size_t)l * NF2 * KP2, scr, NF, HK,
                b1 + (size_t)l * HK, 1);
            mfma_gemm2<<<gf, 512, gemm_lds, stream>>>(
                scr, NF, W2t + (size_t)l * NF2 * KP2, dch, NF, DD,
                b2 + (size_t)l * DD, 0);
            add_ln_kernel<<<lnGrid, 256, 0, stream>>>(dch, xc, ln2g + l * DD, ln2b + l * DD, rows);
        }
        final_kernel<<<bch, 256, 0, stream>>>(xc, Wc, bc, out + (size_t)c * bch);
    }
}

// Round 9
// 1974.090 us; speedup vs baseline: 5.2067x; 1.0778x over previous
//
#include <hip/hip_runtime.h>
#include <hip/hip_bf16.h>
#include <math.h>

typedef __hip_bfloat16 bf16;
typedef __bf16 bf16x8 __attribute__((ext_vector_type(8)));
typedef __bf16 bf16x4 __attribute__((ext_vector_type(4)));
typedef float floatx4 __attribute__((ext_vector_type(4)));

#define BB 512
#define TT 80
#define DD 540
#define HH 6
#define KK 90
#define LL 6
#define HK 540      // H*K (real)
#define KKA 96      // head size padded to 96 (16B-aligned bf16x8 groups)
#define HKA 576     // H*KKA
#define NQA 1728    // 3*H*KKA  (qkv output ld, aligned head layout)
#define BT 40960    // B*T
#define TD 43200    // T*D
#define KP2 576     // GEMM K padded (18 * 32)
#define NQ2 1792    // qkv N padded to 256 (7 * 256)
#define NF 640      // ff output ld / padded N (5 * 128)
#define TP 104      // attn LDS row stride (96 + 8 pad)
#define NKT2 18     // KP2 / 32

__device__ inline float toF(bf16 x) { return __bfloat162float(x); }

// ---------------- weight prep (runs every launch; graph-safe) ----------------

// QKV weights in aligned-head layout: n = sel*HKA + h*KKA + kk, zero for kk>=KK.
__global__ void prep_wqkv(const float* __restrict__ Wq,
                          const float* __restrict__ Wk,
                          const float* __restrict__ Wv,
                          bf16* __restrict__ wTt) {
    int idx = blockIdx.x * blockDim.x + threadIdx.x;
    const int total = LL * NQ2 * KP2;
    if (idx >= total) return;
    int k = idx % KP2;
    int n = (idx / KP2) % NQ2;
    int l = idx / (KP2 * NQ2);
    float v = 0.f;
    if (k < DD && n < NQA) {
        int sel = n / HKA;
        int nn = n - sel * HKA;
        int h = nn / KKA, kk = nn - h * KKA;
        if (kk < KK) {
            const float* W = (sel == 0) ? Wq : ((sel == 1) ? Wk : Wv);
            v = W[(((size_t)l * HH + h) * DD + k) * KK + kk];
        }
    }
    wTt[idx] = __float2bfloat16(v);
}

__global__ void prep_wt(const float* __restrict__ W, bf16* __restrict__ Wt) {
    int idx = blockIdx.x * blockDim.x + threadIdx.x;
    const int total = LL * NF * KP2;
    if (idx >= total) return;
    int k = idx % KP2;
    int n = (idx / KP2) % NF;
    int l = idx / (KP2 * NF);
    float v = 0.f;
    if (k < DD && n < DD)
        v = W[((size_t)l * DD + k) * DD + n];
    Wt[idx] = __float2bfloat16(v);
}

__global__ void embed_kernel(const int* __restrict__ ids,
                             const float* __restrict__ embed,
                             const float* __restrict__ pos,
                             bf16* __restrict__ xc, int rows) {
    int idx = blockIdx.x * blockDim.x + threadIdx.x;
    int total = rows * KP2;
    if (idx >= total) return;
    int d = idx % KP2;
    int bt = idx / KP2;
    float v = 0.f;
    if (d < DD) {
        int t = bt % TT;
        v = embed[(size_t)ids[bt] * DD + d] + pos[t * DD + d];
    }
    xc[idx] = __float2bfloat16(v);
}

// ---------------- 128xBN BK=32 TRIPLE-buffered MFMA GEMM, 2 blocks/CU ----------------
// Template BN=256 (QKV: 8 waves 2Mx4N, wave 64x64, acc 64 VGPR) or BN=128
// (FF: 4Mx2N, wave 32x64, acc 32 VGPR). Per buffer: A[128][32] + B[BN][32].
// LDS[row][c16] = global[row][c16 ^ ((row>>1)&3)] -> 0 bank conflicts (verified).
// Prefetch DISTANCE 2 (stage tile kt+2 each iter); counted vmcnt(L) waits only
// tile kt+1 (issued a full iteration earlier -> latency covered); never drain
// to 0 mid-loop. One barrier per tile.
// Hazards: stage(kt+2) target = tile kt-1's buffer, readers retired before the
// end-of-(kt-1) barrier; reads of tile kt published by kt-1's vmcnt(L)+barrier.

template<int BN>
__device__ inline void stageT(const bf16* __restrict__ Ab, int lda,
                              const bf16* __restrict__ Bb,
                              bf16* ldsbuf, int k0, int tid) {
    constexpr int LPT = (128 + BN) / 128;        // 16B-chunk loads per thread
#pragma unroll
    for (int i = 0; i < LPT; ++i) {
        int s = tid + i * 512;
        int isB = (s >= 512) ? 1 : 0;            // wave-uniform per i
        int s2 = s - isB * 512;
        int row = s2 >> 2, c = s2 & 3;
        int cs = c ^ ((row >> 1) & 3);           // pre-swizzled global chunk
        const bf16* src = isB ? (Bb + (size_t)row * KP2 + k0 + cs * 8)
                              : (Ab + (size_t)row * lda + k0 + cs * 8);
        bf16* dst = ldsbuf + isB * 4096 + s2 * 8;
        __builtin_amdgcn_global_load_lds(
            (const __attribute__((address_space(1))) void*)src,
            (__attribute__((address_space(3))) void*)dst, 16, 0, 0);
    }
}

template<int BN>
__global__ __launch_bounds__(512, 4) void mfma_gemm2(
    const bf16* __restrict__ A, int lda,
    const bf16* __restrict__ Bt,
    bf16* __restrict__ C, int ldc, int Nreal,
    const float* __restrict__ bias, int relu)
{
    constexpr int WCN = BN / 64;                 // waves in N: 4 or 2
    constexpr int WM  = 8 / WCN;                 // waves in M: 2 or 4
    constexpr int MR  = 128 / (WM * 16);         // A frags per wave: 4 or 2
    constexpr int BUFSZ_ = (128 + BN) * 32;      // bf16 per buffer
    extern __shared__ __align__(16) bf16 ldsb[]; // 3 * BUFSZ_
    const int tid = threadIdx.x;
    const int lane = tid & 63;
    const int wave = tid >> 6;
    const int wr = wave / WCN;                   // M group
    const int wc = wave % WCN;                   // N group (64 cols each)
    const int q = lane >> 4, r = lane & 15;

    // bijective XCD swizzle (only when grid % 8 == 0)
    int bx = blockIdx.x, by = blockIdx.y;
    {
        int nwg = gridDim.x * gridDim.y;
        if ((nwg & 7) == 0) {
            int orig = by * gridDim.x + bx;
            int per = nwg >> 3;
            int swz = (orig & 7) * per + (orig >> 3);
            bx = swz % gridDim.x;
            by = swz / gridDim.x;
        }
    }
    const int row0 = by * 128;
    const int col0 = bx * BN;

    floatx4 acc[MR][4];
#pragma unroll
    for (int i = 0; i < MR; ++i)
#pragma unroll
        for (int j = 0; j < 4; ++j) acc[i][j] = (floatx4){0.f, 0.f, 0.f, 0.f};

    const bf16* Ab = A + (size_t)row0 * lda;
    const bf16* Bb = Bt + (size_t)col0 * KP2;

    const int ksw = (q ^ ((r >> 1) & 3)) * 8;    // read-side chunk swizzle

    bf16* bp0 = ldsb;
    bf16* bp1 = ldsb + BUFSZ_;
    bf16* bp2 = ldsb + 2 * BUFSZ_;

    // prologue: stage tiles 0 and 1; wait tile 0 only (counted), publish
    stageT<BN>(Ab, lda, Bb, bp0, 0, tid);
    stageT<BN>(Ab, lda, Bb, bp1, 32, tid);
    if constexpr (BN == 256) asm volatile("s_waitcnt vmcnt(3)" ::: "memory");
    else                     asm volatile("s_waitcnt vmcnt(2)" ::: "memory");
    __builtin_amdgcn_sched_barrier(0);
    __builtin_amdgcn_s_barrier();
    __builtin_amdgcn_sched_barrier(0);

    for (int kt = 0; kt < NKT2; ++kt) {
        // fire-and-forget: stage tile kt+2 into the buffer freed at tile kt-1
        if (kt + 2 < NKT2)
            stageT<BN>(Ab, lda, Bb, bp2, (kt + 2) * 32, tid);

        bf16x8 a0[MR], b0[4];
#pragma unroll
        for (int i = 0; i < MR; ++i) {
            int row_ = wr * (MR * 16) + i * 16 + r;
            a0[i] = *(const bf16x8*)(bp0 + row_ * 32 + ksw);
        }
#pragma unroll
        for (int j = 0; j < 4; ++j) {
            int row_ = wc * 64 + j * 16 + r;
            b0[j] = *(const bf16x8*)(bp0 + 4096 + row_ * 32 + ksw);
        }

        __builtin_amdgcn_s_setprio(1);
#pragma unroll
        for (int i = 0; i < MR; ++i)
#pragma unroll
            for (int j = 0; j < 4; ++j)
                acc[i][j] = __builtin_amdgcn_mfma_f32_16x16x32_bf16(
                    a0[i], b0[j], acc[i][j], 0, 0, 0);
        __builtin_amdgcn_s_setprio(0);

        // counted wait: only tile kt+1 (issued last iteration) must be landed
        if (kt + 2 < NKT2) {
            if constexpr (BN == 256) asm volatile("s_waitcnt vmcnt(3)" ::: "memory");
            else                     asm volatile("s_waitcnt vmcnt(2)" ::: "memory");
        } else {
            asm volatile("s_waitcnt vmcnt(0)" ::: "memory");
        }
        __builtin_amdgcn_sched_barrier(0);
        __builtin_amdgcn_s_barrier();
        __builtin_amdgcn_sched_barrier(0);

        bf16* t = bp0; bp0 = bp1; bp1 = bp2; bp2 = t;   // rotate
    }

    // epilogue
#pragma unroll
    for (int mi = 0; mi < MR; ++mi) {
        int m0 = row0 + wr * (MR * 16) + mi * 16 + q * 4;
#pragma unroll
        for (int ni = 0; ni < 4; ++ni) {
            int n = col0 + wc * 64 + ni * 16 + r;
            if (n < ldc) {
                bool valid = (n < Nreal);
                float bv = (valid && bias) ? bias[n] : 0.f;
#pragma unroll
                for (int reg = 0; reg < 4; ++reg) {
                    float v = acc[mi][ni][reg] + bv;
                    if (relu) v = fmaxf(v, 0.f);
                    if (!valid) v = 0.f;
                    C[(size_t)(m0 + reg) * ldc + n] = __float2bfloat16(v);
                }
            }
        }
    }
}

// ---------------- MFMA attention (aligned-head qkv layout, vectorized staging) ----------------
__global__ __launch_bounds__(320) void attn_mfma(const bf16* __restrict__ qkv,
                                                 bf16* __restrict__ obuf) {
    extern __shared__ bf16 lds[];
    bf16* Qs = lds;                    // 80*TP
    bf16* Ks = lds + 80 * TP;          // 80*TP (becomes P)
    bf16* Vt = lds + 160 * TP;         // 96*TP
    __bf16* Vtb = (__bf16*)Vt;
    const int b = blockIdx.x / HH, h = blockIdx.x % HH;
    const int tid = threadIdx.x;
    const int lane = tid & 63;
    const int w = tid >> 6;            // wave 0..4
    const int q = lane >> 4, r = lane & 15;
    const bf16* base = qkv + (size_t)b * TT * NQA + h * KKA;

    // stage Q, K (pad cols [90,96) are zero in qkv by construction); V transposed
    for (int i = tid; i < TT * 12; i += 320) {
        int t = i / 12, kg = i % 12;
        const bf16* qr2 = base + (size_t)t * NQA + kg * 8;
        bf16x8 qv = *(const bf16x8*)qr2;
        bf16x8 kv2 = *(const bf16x8*)(qr2 + HKA);
        bf16x8 vv = *(const bf16x8*)(qr2 + 2 * HKA);
        *(bf16x8*)(Qs + t * TP + kg * 8) = qv;
        *(bf16x8*)(Ks + t * TP + kg * 8) = kv2;
#pragma unroll
        for (int j = 0; j < 8; ++j)
            Vtb[(kg * 8 + j) * TP + t] = vv[j];
    }
    // zero Vt s-pad [80,96) so PV pad terms are exactly 0
    for (int i = tid; i < 96 * 2; i += 320) {
        int kv = i >> 1, sg = i & 1;
        *(bf16x8*)(Vt + kv * TP + 80 + sg * 8) = (bf16x8)(__bf16)0.0f;
    }
    __syncthreads();

    // S-GEMM: wave w -> columns s in [16w, 16w+16)
    floatx4 acc[5];
#pragma unroll
    for (int i = 0; i < 5; ++i) acc[i] = (floatx4){0.f, 0.f, 0.f, 0.f};
    bf16x8 bf[3];
#pragma unroll
    for (int ks = 0; ks < 3; ++ks)
        bf[ks] = *(const bf16x8*)(Ks + (16 * w + r) * TP + ks * 32 + q * 8);
#pragma unroll
    for (int ti = 0; ti < 5; ++ti) {
#pragma unroll
        for (int ks = 0; ks < 3; ++ks) {
            bf16x8 af = *(const bf16x8*)(Qs + (16 * ti + r) * TP + ks * 32 + q * 8);
            acc[ti] = __builtin_amdgcn_mfma_f32_16x16x32_bf16(af, bf[ks], acc[ti], 0, 0, 0);
        }
    }

    const float scale = 0.105409255338946f;  // 90^-0.5
    float m = -1e30f;
#pragma unroll
    for (int ti = 0; ti < 5; ++ti)
#pragma unroll
        for (int reg = 0; reg < 4; ++reg) {
            acc[ti][reg] *= scale;
            m = fmaxf(m, acc[ti][reg]);
        }
    m = fmaxf(m, __shfl_xor(m, 16));
    m = fmaxf(m, __shfl_xor(m, 32));
    float sum = 0.f;
    float e[5][4];
#pragma unroll
    for (int ti = 0; ti < 5; ++ti)
#pragma unroll
        for (int reg = 0; reg < 4; ++reg) {
            e[ti][reg] = __expf(acc[ti][reg] - m);
            sum += e[ti][reg];
        }
    sum += __shfl_xor(sum, 16);
    sum += __shfl_xor(sum, 32);
    float inv = 1.f / sum;

    __syncthreads();   // all Ks reads done before P overwrites it

    bf16* P = Ks;
#pragma unroll
    for (int ti = 0; ti < 5; ++ti)
#pragma unroll
        for (int reg = 0; reg < 4; ++reg)
            P[(16 * ti + q * 4 + reg) * TP + 16 * w + r] =
                __float2bfloat16(e[ti][reg] * inv);
    for (int i = tid; i < TT * 2; i += 320) {
        int t2 = i >> 1, sg = i & 1;
        *(bf16x8*)(P + t2 * TP + 80 + sg * 8) = (bf16x8)(__bf16)0.0f;
    }
    __syncthreads();

    bf16x8 af2[3];
#pragma unroll
    for (int ks = 0; ks < 3; ++ks)
        af2[ks] = *(const bf16x8*)(P + (16 * w + r) * TP + ks * 32 + q * 8);
    bf16* ob = obuf + ((size_t)b * TT) * NF + h * KK;
#pragma unroll
    for (int nt = 0; nt < 6; ++nt) {
        floatx4 o = (floatx4){0.f, 0.f, 0.f, 0.f};
#pragma unroll
        for (int ks = 0; ks < 3; ++ks) {
            bf16x8 bv = *(const bf16x8*)(Vt + (16 * nt + r) * TP + ks * 32 + q * 8);
            o = __builtin_amdgcn_mfma_f32_16x16x32_bf16(af2[ks], bv, o, 0, 0, 0);
        }
        int kv = 16 * nt + r;
        if (kv < KK) {
#pragma unroll
            for (int reg = 0; reg < 4; ++reg) {
                int t2 = 16 * w + q * 4 + reg;
                ob[(size_t)t2 * NF + kv] = __float2bfloat16(o[reg]);
            }
        }
    }
}

// ---------------- x = LN(delta + x) * g + b  — one wave per row, vectorized ----------------
__global__ __launch_bounds__(256) void add_ln_kernel(const bf16* __restrict__ delta,
                                                     bf16* __restrict__ x,
                                                     const float* __restrict__ g,
                                                     const float* __restrict__ bta,
                                                     int nrows) {
    const int w = threadIdx.x >> 6;
    const int lane = threadIdx.x & 63;
    const int row = blockIdx.x * 4 + w;
    if (row >= nrows) return;
    const bf16* dr = delta + (size_t)row * NF;
    bf16* xr = x + (size_t)row * KP2;

    float v[3][4];
    float s1 = 0.f, s2 = 0.f;
#pragma unroll
    for (int s = 0; s < 3; ++s) {
        int c = s * 256 + lane * 4;
        if (c < DD) {
            bf16x4 dv = *(const bf16x4*)(dr + c);
            bf16x4 xv = *(const bf16x4*)(xr + c);
#pragma unroll
            for (int j = 0; j < 4; ++j) {
                float t = (float)dv[j] + (float)xv[j];
                v[s][j] = t;
                s1 += t; s2 += t * t;
            }
        } else {
#pragma unroll
            for (int j = 0; j < 4; ++j) v[s][j] = 0.f;
        }
    }
#pragma unroll
    for (int o = 32; o > 0; o >>= 1) {
        s1 += __shfl_xor(s1, o, 64);
        s2 += __shfl_xor(s2, o, 64);
    }
    const float mean = s1 * (1.f / DD);
    const float var = s2 * (1.f / DD) - mean * mean;
    const float rstd = rsqrtf(var + 1e-5f);
#pragma unroll
    for (int s = 0; s < 3; ++s) {
        int c = s * 256 + lane * 4;
        if (c < DD) {
            float4 gv = *(const float4*)(g + c);
            float4 bv = *(const float4*)(bta + c);
            bf16x4 ov;
            ov[0] = (__bf16)((v[s][0] - mean) * rstd * gv.x + bv.x);
            ov[1] = (__bf16)((v[s][1] - mean) * rstd * gv.y + bv.y);
            ov[2] = (__bf16)((v[s][2] - mean) * rstd * gv.z + bv.z);
            ov[3] = (__bf16)((v[s][3] - mean) * rstd * gv.w + bv.w);
            *(bf16x4*)(xr + c) = ov;
        }
    }
}

__global__ __launch_bounds__(256) void final_kernel(const bf16* __restrict__ xc,
                                                    const float* __restrict__ Wc,
                                                    const float* __restrict__ bc,
                                                    float* __restrict__ out) {
    int b = blockIdx.x;
    int tid = threadIdx.x;
    const bf16* xb = xc + (size_t)b * TT * KP2;
    float s = 0.f;
    for (int i = tid; i < TD; i += 256) {
        int t = i / DD, d = i - t * DD;
        s += toF(xb[(size_t)t * KP2 + d]) * Wc[i];
    }
    for (int o = 32; o > 0; o >>= 1) s += __shfl_down(s, o, 64);
    __shared__ float red[4];
    int lane = tid & 63, w = tid >> 6;
    if (lane == 0) red[w] = s;
    __syncthreads();
    if (tid == 0) out[b] = red[0] + red[1] + red[2] + red[3] + bc[0];
}

extern "C" void kernel_launch(void* const* d_in, const int* in_sizes, int n_in,
                              void* d_out, int out_size, void* d_ws, size_t ws_size,
                              hipStream_t stream) {
    const int* ids    = (const int*)d_in[0];
    const float* embed = (const float*)d_in[1];
    const float* pos  = (const float*)d_in[2];
    const float* Wq   = (const float*)d_in[3];
    const float* Wk   = (const float*)d_in[4];
    const float* Wv   = (const float*)d_in[5];
    const float* W1   = (const float*)d_in[6];
    const float* b1   = (const float*)d_in[7];
    const float* W2   = (const float*)d_in[8];
    const float* b2   = (const float*)d_in[9];
    const float* ln1g = (const float*)d_in[10];
    const float* ln1b = (const float*)d_in[11];
    const float* ln2g = (const float*)d_in[12];
    const float* ln2b = (const float*)d_in[13];
    const float* Wc   = (const float*)d_in[14];
    const float* bc   = (const float*)d_in[15];
    float* out = (float*)d_out;

    const size_t wqkvB = (size_t)LL * NQ2 * KP2 * 2;
    const size_t wffB  = (size_t)LL * NF * KP2 * 2;
    const size_t fixed = wqkvB + 2 * wffB;
    const size_t perB  = (size_t)TT * 2 * (KP2 + NQA + NF);

    int bch = BB;
    while (bch > 16 && fixed + (size_t)bch * perB > ws_size) bch >>= 1;
    int nch = BB / bch;
    int rows = bch * TT;           // multiple of 256 for bch >= 16

    char* p = (char*)d_ws;
    bf16* wTt = (bf16*)p;  p += wqkvB;
    bf16* W1t = (bf16*)p;  p += wffB;
    bf16* W2t = (bf16*)p;  p += wffB;
    bf16* xc  = (bf16*)p;  p += (size_t)rows * KP2 * 2;
    bf16* scr = (bf16*)p;  p += (size_t)rows * NQA * 2;
    bf16* dch = (bf16*)p;

    prep_wqkv<<<(LL * NQ2 * KP2 + 255) / 256, 256, 0, stream>>>(Wq, Wk, Wv, wTt);
    prep_wt<<<(LL * NF * KP2 + 255) / 256, 256, 0, stream>>>(W1, W1t);
    prep_wt<<<(LL * NF * KP2 + 255) / 256, 256, 0, stream>>>(W2, W2t);

    dim3 gq(NQ2 / 256, rows / 128);
    dim3 gf(NF / 128, rows / 128);
    const size_t gemm_lds_q = 3 * (128 + 256) * 32 * sizeof(bf16);  // 72 KiB
    const size_t gemm_lds_f = 3 * (128 + 128) * 32 * sizeof(bf16);  // 48 KiB
    const size_t attn_lds = (size_t)(160 + 96) * TP * 2;   // 53,248 B
    const int lnGrid = (rows + 3) / 4;

    for (int c = 0; c < nch; ++c) {
        embed_kernel<<<(rows * KP2 + 255) / 256, 256, 0, stream>>>(
            ids + (size_t)c * rows, embed, pos, xc, rows);
        for (int l = 0; l < LL; ++l) {
            mfma_gemm2<256><<<gq, 512, gemm_lds_q, stream>>>(
                xc, KP2, wTt + (size_t)l * NQ2 * KP2, scr, NQA, NQA,
                (const float*)nullptr, 0);
            attn_mfma<<<bch * HH, 320, attn_lds, stream>>>(scr, dch);
            add_ln_kernel<<<lnGrid, 256, 0, stream>>>(dch, xc, ln1g + l * DD, ln1b + l * DD, rows);
            mfma_gemm2<128><<<gf, 512, gemm_lds_f, stream>>>(
                xc, KP2, W1t + (size_t)l * NF * KP2, scr, NF, HK,
                b1 + (size_t)l * HK, 1);
            mfma_gemm2<128><<<gf, 512, gemm_lds_f, stream>>>(
                scr, NF, W2t + (size_t)l * NF * KP2, dch, NF, DD,
                b2 + (size_t)l * DD, 0);
            add_ln_kernel<<<lnGrid, 256, 0, stream>>>(dch, xc, ln2g + l * DD, ln2b + l * DD, rows);
        }
        final_kernel<<<bch, 256, 0, stream>>>(xc, Wc, bc, out + (size_t)c * bch);
    }
}